// Round 10
// baseline (123.102 us; speedup 1.0000x reference)
//
#include <hip/hip_runtime.h>

// Binarized conv block via i8 MFMA implicit GEMM.
//   a = sign(x+bias1) in {+1,-1} (i8), zero-padded image [32][58][58][256] i8
//   qk = sign(kernel) in {+1,-1} (i8), pre-transposed to W_t[co][k]
//   conv == GEMM: C[pixel][co] = sum_k A_im2col[pixel][k] * W[k][co]
//   out = relu(C*scale[co] + shift[co])   (folded BN + bias2)
// i8 zero-pad == true conv zero-pad -> exact integers, no edge corrections.
//
// R9 -> R10: R9's 2-buffer loop still drained vmcnt(0) at every barrier
// (prefetch issued only ~1 compute-phase earlier; MfmaUtil 25%). R10 = T3/T4:
// 3-deep buffer rotation, loads issued TWO steps ahead, counted vmcnt(12)
// (= 2 stages in flight x 6 loads) + raw s_barrier — stage(s) landed long ago,
// queue never drains. Tail: vmcnt(6)/vmcnt(0). Raw barrier + asm memory
// fences keep hipcc from inserting its own vmcnt(0) drain (the m97 ceiling).

typedef int v4i __attribute__((ext_vector_type(4)));
typedef unsigned int u32;

#define NB   32
#define HW   56
#define HP   58
#define HP2  (HP*HP)             // 3364
#define CIN  256
#define COUT 256
#define NPIX (NB*HW*HW)          // 100352
#define KTOT 2304
#define BM   128                 // pixels per block
#define NSTEP 36                 // K steps of 64

#define PA_BYTES ((size_t)NB*HP*HP*CIN)     // 27,557,888
#define WT_OFF   PA_BYTES
#define WT_BYTES ((size_t)KTOT*COUT)        // 589,824
#define SC_OFF   (WT_OFF + WT_BYTES)
#define SH_OFF   (SC_OFF + 1024)

__device__ __forceinline__ void g2l16(const void* g, void* l) {
    __builtin_amdgcn_global_load_lds(
        (const __attribute__((address_space(1))) void*)g,
        (__attribute__((address_space(3))) void*)l, 16, 0, 0);
}

// ------- pack activations incl. pad ring: sign(x+bias1) or 0 -> i8 -------
__global__ __launch_bounds__(256) void pack_a_kernel(
    const float* __restrict__ x, const float* __restrict__ b1,
    signed char* __restrict__ pa)
{
    const int lane = threadIdx.x & 63;
    const int pp = blockIdx.x * 4 + (threadIdx.x >> 6);   // padded pixel
    const int n = pp / HP2, r = pp % HP2, ph = r / HP, pw = r % HP;
    const int ci = lane * 4;
    u32 o = 0;
    if (ph >= 1 && ph <= HW && pw >= 1 && pw <= HW) {     // wave-uniform branch
        const int pix = (n * HW + ph - 1) * HW + (pw - 1);
        const float4 xv = *(const float4*)(x + (size_t)pix * CIN + ci);
        const float4 bv = *(const float4*)(b1 + ci);
        o  = (u32)(unsigned char)((xv.x + bv.x >= 0.f) ? 1 : -1);
        o |= (u32)(unsigned char)((xv.y + bv.y >= 0.f) ? 1 : -1) << 8;
        o |= (u32)(unsigned char)((xv.z + bv.z >= 0.f) ? 1 : -1) << 16;
        o |= (u32)(unsigned char)((xv.w + bv.w >= 0.f) ? 1 : -1) << 24;
    }
    *(u32*)(pa + (size_t)pp * CIN + ci) = o;
    // grid = NB*HP*HP/4 = 26912
}

// ---------------- pack + transpose weights: W_t[co][k] i8 ----------------
__global__ __launch_bounds__(256) void packw_kernel(
    const float* __restrict__ k, signed char* __restrict__ wt)
{
    __shared__ signed char tile[64][256];
    const int t = threadIdx.x, k0 = blockIdx.x * 64;
    for (int j = 0; j < 64; ++j)
        tile[j][t] = (k[(size_t)(k0 + j) * COUT + t] >= 0.f) ? 1 : -1;
    __syncthreads();
    u32 wd[16];
#pragma unroll
    for (int j = 0; j < 16; ++j) wd[j] = 0;
#pragma unroll
    for (int j = 0; j < 64; ++j)
        wd[j >> 2] |= ((u32)(unsigned char)tile[j][t]) << ((j & 3) * 8);
    uint4* dst = (uint4*)(wt + (size_t)t * KTOT + k0);
#pragma unroll
    for (int j = 0; j < 4; ++j)
        dst[j] = make_uint4(wd[4*j], wd[4*j+1], wd[4*j+2], wd[4*j+3]);
    // grid = KTOT/64 = 36
}

// ---------------- fold BN + bias2 ----------------
__global__ __launch_bounds__(256) void bnprep_kernel(
    const float* __restrict__ beta, const float* __restrict__ mean,
    const float* __restrict__ var, const float* __restrict__ b2,
    float* __restrict__ scale, float* __restrict__ shift)
{
    const int t = threadIdx.x;
    const float s = rsqrtf(var[t] + 1e-3f);
    scale[t] = s;
    shift[t] = beta[t] - mean[t] * s + b2[t];
}

// ---------------- i8 implicit-GEMM conv + BN + relu ----------------
// 256 thr (4 waves); BM=128 pixels x 256 couts; wave v owns couts [v*64,+64):
// acc[8][4], 32 mfma_i32_16x16x64_i8 per step. 3-deep LDS pipeline.
__global__ __launch_bounds__(256, 2) void conv_mfma_kernel(
    const signed char* __restrict__ pa, const signed char* __restrict__ wt,
    const float* __restrict__ scale, const float* __restrict__ shift,
    float* __restrict__ out)
{
    __shared__ signed char Al[3][BM * 64];     // 3 x 8 KB, [pixel][k64] chunks
    __shared__ signed char Bl[3][COUT * 64];   // 3 x 16 KB, [co][k64] chunks

    const int t = threadIdx.x, l = t & 63, v = t >> 6;
    const int p0 = blockIdx.x * BM;

    // A staging: thread t stages chunk (t&3) of pixels q and q+64 (q = t>>2)
    const signed char* abase[2];
#pragma unroll
    for (int i = 0; i < 2; ++i) {
        const int q = (t >> 2) + i * 64;
        const int p = p0 + q;
        const int n = p / 3136, r = p % 3136, h = r / 56, w = r % 56;
        const int aswz = (((t & 3) ^ ((q >> 1) & 3)) << 4);  // source pre-swizzle
        abase[i] = pa + ((size_t)(n * HP + h) * HP + w) * CIN + aswz;
    }

    // B staging: call j stages (co = v*64 + j*16 + l/4, chunk l&3)
    const signed char* wbase[4];
#pragma unroll
    for (int j = 0; j < 4; ++j) {
        const int co = v * 64 + j * 16 + (l >> 2);
        const int bswz = (((l & 3) ^ ((co >> 1) & 3)) << 4);
        wbase[j] = wt + (size_t)co * KTOT + bswz;
    }

    // fragment ds_read byte offsets (swizzled reads matching pre-swizzled src)
    int aoff[8], boff[4];
#pragma unroll
    for (int pg = 0; pg < 8; ++pg) {
        const int row = pg * 16 + (l & 15);
        aoff[pg] = row * 64 + ((((l >> 4) ^ (row >> 1)) & 3) << 4);
    }
#pragma unroll
    for (int cg = 0; cg < 4; ++cg) {
        const int row = v * 64 + cg * 16 + (l & 15);
        boff[cg] = row * 64 + ((((l >> 4) ^ (row >> 1)) & 3) << 4);
    }

    v4i acc[8][4];
#pragma unroll
    for (int i = 0; i < 8; ++i)
#pragma unroll
        for (int j = 0; j < 4; ++j) acc[i][j] = (v4i){0, 0, 0, 0};

    auto STAGE = [&](int buf, int s) {
        const int tap = s >> 2, cq = s & 3;
        const int ty = tap / 3, tx = tap - ty * 3;
        const int goff = ((ty * HP + tx) << 8) + (cq << 6);
        g2l16(abase[0] + goff, &Al[buf][v * 1024]);
        g2l16(abase[1] + goff, &Al[buf][4096 + v * 1024]);
#pragma unroll
        for (int j = 0; j < 4; ++j)
            g2l16(wbase[j] + (s << 6), &Bl[buf][v * 4096 + j * 1024]);
    };
    auto COMPUTE = [&](int cur) {
        v4i af[8], bf[4];
#pragma unroll
        for (int pg = 0; pg < 8; ++pg) af[pg] = *(const v4i*)(&Al[cur][aoff[pg]]);
#pragma unroll
        for (int cg = 0; cg < 4; ++cg) bf[cg] = *(const v4i*)(&Bl[cur][boff[cg]]);
#pragma unroll
        for (int pg = 0; pg < 8; ++pg)
#pragma unroll
            for (int cg = 0; cg < 4; ++cg)
                acc[pg][cg] = __builtin_amdgcn_mfma_i32_16x16x64_i8(
                    af[pg], bf[cg], acc[pg][cg], 0, 0, 0);
    };

    // prologue: two stages in flight
    STAGE(0, 0);
    STAGE(1, 1);
    // main loop: stage s+2, wait stage(s) landed (12 = 2 stages x 6 loads
    // still allowed in flight), barrier, compute s. Never drains to 0.
#pragma unroll 1
    for (int s = 0; s < NSTEP - 2; ++s) {
        STAGE((s + 2) % 3, s + 2);
        asm volatile("s_waitcnt vmcnt(12)" ::: "memory");
        __builtin_amdgcn_s_barrier();
        asm volatile("" ::: "memory");
        COMPUTE(s % 3);
        asm volatile("" ::: "memory");
        __builtin_amdgcn_s_barrier();      // all waves done reading buf s%3
        asm volatile("" ::: "memory");     // (it's restaged at iter s+1)
    }
    // tail: s = NSTEP-2 (stage NSTEP-1 still in flight), then s = NSTEP-1
    asm volatile("s_waitcnt vmcnt(6)" ::: "memory");
    __builtin_amdgcn_s_barrier();
    asm volatile("" ::: "memory");
    COMPUTE((NSTEP - 2) % 3);
    asm volatile("s_waitcnt vmcnt(0)" ::: "memory");
    __builtin_amdgcn_s_barrier();
    asm volatile("" ::: "memory");
    COMPUTE((NSTEP - 1) % 3);

    // epilogue: C col = l&15 (co), row = (l>>4)*4 + reg (pixel)   [m89 layout]
#pragma unroll
    for (int cg = 0; cg < 4; ++cg) {
        const int co = v * 64 + cg * 16 + (l & 15);
        const float sc = scale[co], sh = shift[co];
#pragma unroll
        for (int pg = 0; pg < 8; ++pg) {
            const int prow0 = p0 + pg * 16 + (l >> 4) * 4;
#pragma unroll
            for (int rr = 0; rr < 4; ++rr) {
                const float y = (float)acc[pg][cg][rr];
                out[(size_t)(prow0 + rr) * COUT + co] = fmaxf(fmaf(y, sc, sh), 0.f);
            }
        }
    }
}

extern "C" void kernel_launch(void* const* d_in, const int* in_sizes, int n_in,
                              void* d_out, int out_size, void* d_ws, size_t ws_size,
                              hipStream_t stream)
{
    const float* x      = (const float*)d_in[0];
    const float* bias1  = (const float*)d_in[1];
    const float* kernel = (const float*)d_in[2];
    const float* bn_beta = (const float*)d_in[3];
    const float* bn_mean = (const float*)d_in[4];
    const float* bn_var  = (const float*)d_in[5];
    const float* bias2   = (const float*)d_in[6];
    float* out = (float*)d_out;

    signed char* pa  = (signed char*)d_ws;                // padded i8 image
    signed char* wtp = (signed char*)d_ws + WT_OFF;       // W_t[co][k]
    float* scale = (float*)((char*)d_ws + SC_OFF);
    float* shift = (float*)((char*)d_ws + SH_OFF);

    pack_a_kernel<<<dim3(NB * HP2 / 4), dim3(256), 0, stream>>>(x, bias1, pa);
    packw_kernel<<<dim3(KTOT / 64), dim3(256), 0, stream>>>(kernel, wtp);
    bnprep_kernel<<<dim3(1), dim3(256), 0, stream>>>(bn_beta, bn_mean, bn_var, bias2,
                                                     scale, shift);
    conv_mfma_kernel<<<dim3(NPIX / BM), dim3(256), 0, stream>>>(pa, wtp, scale, shift, out);
}

// Round 11
// 110.729 us; speedup vs baseline: 1.1117x; 1.1117x over previous
//
#include <hip/hip_runtime.h>

// Binarized conv block via i8 MFMA implicit GEMM.
//   a = sign(x+bias1) in {+1,-1} (i8), zero-padded image [32][58][58][256] i8
//   qk = sign(kernel) in {+1,-1} (i8), pre-transposed to W_t[co][k]
//   conv == GEMM: C[pixel][co] = sum_k A_im2col[pixel][k] * W[k][co]
//   out = relu(C*scale[co] + shift[co])   (folded BN + bias2)
// i8 zero-pad == true conv zero-pad -> exact integers, no edge corrections.
//
// R8-R10 all landed at MfmaUtil 22-25% (the measured 2-phase wall, m233);
// coarse split / counted-vmcnt grafts are null outside the 8-phase interleave
// (m196/m218b regime gate). R11 ports the 8-phase template: per K-step, two
// phases of {ds_read subtile; issue 3 global_load_lds; barrier; setprio(1);
// 16 MFMA; setprio(0); barrier}; ONE counted vmcnt(6) per step at the
// trailing barrier (stage s+2 stays in flight; never drain to 0 mid-loop).
// 3-deep LDS rotation; stage into (s+2)%3 only after the trailing barrier
// that follows the last read of that buffer (race-free).

typedef int v4i __attribute__((ext_vector_type(4)));
typedef unsigned int u32;

#define NB   32
#define HW   56
#define HP   58
#define HP2  (HP*HP)             // 3364
#define CIN  256
#define COUT 256
#define NPIX (NB*HW*HW)          // 100352
#define KTOT 2304
#define BM   128                 // pixels per block
#define NSTEP 36                 // K steps of 64

#define PA_BYTES ((size_t)NB*HP*HP*CIN)     // 27,557,888
#define WT_OFF   PA_BYTES
#define WT_BYTES ((size_t)KTOT*COUT)        // 589,824
#define SC_OFF   (WT_OFF + WT_BYTES)
#define SH_OFF   (SC_OFF + 1024)

__device__ __forceinline__ void g2l16(const void* g, void* l) {
    __builtin_amdgcn_global_load_lds(
        (const __attribute__((address_space(1))) void*)g,
        (__attribute__((address_space(3))) void*)l, 16, 0, 0);
}

// ------- pack activations incl. pad ring: sign(x+bias1) or 0 -> i8 -------
__global__ __launch_bounds__(256) void pack_a_kernel(
    const float* __restrict__ x, const float* __restrict__ b1,
    signed char* __restrict__ pa)
{
    const int lane = threadIdx.x & 63;
    const int pp = blockIdx.x * 4 + (threadIdx.x >> 6);   // padded pixel
    const int n = pp / HP2, r = pp % HP2, ph = r / HP, pw = r % HP;
    const int ci = lane * 4;
    u32 o = 0;
    if (ph >= 1 && ph <= HW && pw >= 1 && pw <= HW) {     // wave-uniform branch
        const int pix = (n * HW + ph - 1) * HW + (pw - 1);
        const float4 xv = *(const float4*)(x + (size_t)pix * CIN + ci);
        const float4 bv = *(const float4*)(b1 + ci);
        o  = (u32)(unsigned char)((xv.x + bv.x >= 0.f) ? 1 : -1);
        o |= (u32)(unsigned char)((xv.y + bv.y >= 0.f) ? 1 : -1) << 8;
        o |= (u32)(unsigned char)((xv.z + bv.z >= 0.f) ? 1 : -1) << 16;
        o |= (u32)(unsigned char)((xv.w + bv.w >= 0.f) ? 1 : -1) << 24;
    }
    *(u32*)(pa + (size_t)pp * CIN + ci) = o;
    // grid = NB*HP*HP/4 = 26912
}

// ---------------- pack + transpose weights: W_t[co][k] i8 ----------------
__global__ __launch_bounds__(256) void packw_kernel(
    const float* __restrict__ k, signed char* __restrict__ wt)
{
    __shared__ signed char tile[64][256];
    const int t = threadIdx.x, k0 = blockIdx.x * 64;
    for (int j = 0; j < 64; ++j)
        tile[j][t] = (k[(size_t)(k0 + j) * COUT + t] >= 0.f) ? 1 : -1;
    __syncthreads();
    u32 wd[16];
#pragma unroll
    for (int j = 0; j < 16; ++j) wd[j] = 0;
#pragma unroll
    for (int j = 0; j < 64; ++j)
        wd[j >> 2] |= ((u32)(unsigned char)tile[j][t]) << ((j & 3) * 8);
    uint4* dst = (uint4*)(wt + (size_t)t * KTOT + k0);
#pragma unroll
    for (int j = 0; j < 4; ++j)
        dst[j] = make_uint4(wd[4*j], wd[4*j+1], wd[4*j+2], wd[4*j+3]);
    // grid = KTOT/64 = 36
}

// ---------------- fold BN + bias2 ----------------
__global__ __launch_bounds__(256) void bnprep_kernel(
    const float* __restrict__ beta, const float* __restrict__ mean,
    const float* __restrict__ var, const float* __restrict__ b2,
    float* __restrict__ scale, float* __restrict__ shift)
{
    const int t = threadIdx.x;
    const float s = rsqrtf(var[t] + 1e-3f);
    scale[t] = s;
    shift[t] = beta[t] - mean[t] * s + b2[t];
}

// ---------------- i8 implicit-GEMM conv + BN + relu (8-phase style) -------
__global__ __launch_bounds__(256, 2) void conv_mfma_kernel(
    const signed char* __restrict__ pa, const signed char* __restrict__ wt,
    const float* __restrict__ scale, const float* __restrict__ shift,
    float* __restrict__ out)
{
    __shared__ signed char Al[3][BM * 64];     // 3 x 8 KB
    __shared__ signed char Bl[3][COUT * 64];   // 3 x 16 KB

    const int t = threadIdx.x, l = t & 63, v = t >> 6;
    const int p0 = blockIdx.x * BM;

    // A staging: thread t stages chunk (t&3) of pixels q and q+64 (q = t>>2)
    const signed char* abase[2];
#pragma unroll
    for (int i = 0; i < 2; ++i) {
        const int q = (t >> 2) + i * 64;
        const int p = p0 + q;
        const int n = p / 3136, r = p % 3136, h = r / 56, w = r % 56;
        const int aswz = (((t & 3) ^ ((q >> 1) & 3)) << 4);  // source pre-swizzle
        abase[i] = pa + ((size_t)(n * HP + h) * HP + w) * CIN + aswz;
    }

    // B staging: call j stages (co = v*64 + j*16 + l/4, chunk l&3)
    const signed char* wbase[4];
#pragma unroll
    for (int j = 0; j < 4; ++j) {
        const int co = v * 64 + j * 16 + (l >> 2);
        const int bswz = (((l & 3) ^ ((co >> 1) & 3)) << 4);
        wbase[j] = wt + (size_t)co * KTOT + bswz;
    }

    // fragment ds_read byte offsets (swizzled reads match pre-swizzled src)
    int aoff[8], boff[4];
#pragma unroll
    for (int pg = 0; pg < 8; ++pg) {
        const int row = pg * 16 + (l & 15);
        aoff[pg] = row * 64 + ((((l >> 4) ^ (row >> 1)) & 3) << 4);
    }
#pragma unroll
    for (int cg = 0; cg < 4; ++cg) {
        const int row = v * 64 + cg * 16 + (l & 15);
        boff[cg] = row * 64 + ((((l >> 4) ^ (row >> 1)) & 3) << 4);
    }

    v4i acc[8][4];
#pragma unroll
    for (int i = 0; i < 8; ++i)
#pragma unroll
        for (int j = 0; j < 4; ++j) acc[i][j] = (v4i){0, 0, 0, 0};

    // stage helpers: sA = A-halves + B0 ; sB = B1..B3   (3 vm-items each)
    auto goffA = [&](int s) {
        const int tap = s >> 2, cq = s & 3;
        const int ty = tap / 3, tx = tap - ty * 3;
        return ((ty * HP + tx) << 8) + (cq << 6);
    };
    auto STAGE_P0 = [&](int buf, int s) {
        const int go = goffA(s);
        g2l16(abase[0] + go, &Al[buf][v * 1024]);
        g2l16(abase[1] + go, &Al[buf][4096 + v * 1024]);
        g2l16(wbase[0] + (s << 6), &Bl[buf][v * 4096]);
    };
    auto STAGE_P1 = [&](int buf, int s) {
#pragma unroll
        for (int j = 1; j < 4; ++j)
            g2l16(wbase[j] + (s << 6), &Bl[buf][v * 4096 + j * 1024]);
    };

    // prologue: 2 stages in flight, wait stage(0) landed (6 still in flight)
    STAGE_P0(0, 0); STAGE_P1(0, 0);
    STAGE_P0(1, 1); STAGE_P1(1, 1);
    asm volatile("s_waitcnt vmcnt(6)" ::: "memory");
    __builtin_amdgcn_s_barrier();

    int cur = 0;
#pragma unroll 1
    for (int s = 0; s < NSTEP; ++s) {
        signed char* Ac = &Al[0][0] + cur * (BM * 64);
        signed char* Bc = &Bl[0][0] + cur * (COUT * 64);
        const int stg = (cur >= 1) ? cur - 1 : 2;        // (cur+2)%3
        const bool do_stage = (s + 2 < NSTEP);

        // ---- phase 0: reads + stage issue, then MFMA quadrant 0 ----
        v4i af0 = *(const v4i*)(Ac + aoff[0]);
        v4i af1 = *(const v4i*)(Ac + aoff[1]);
        v4i af2 = *(const v4i*)(Ac + aoff[2]);
        v4i af3 = *(const v4i*)(Ac + aoff[3]);
        v4i bf0 = *(const v4i*)(Bc + boff[0]);
        v4i bf1 = *(const v4i*)(Bc + boff[1]);
        v4i bf2 = *(const v4i*)(Bc + boff[2]);
        v4i bf3 = *(const v4i*)(Bc + boff[3]);
        if (do_stage) STAGE_P0(stg, s + 2);
        asm volatile("" ::: "memory");
        __builtin_amdgcn_s_barrier();
        __builtin_amdgcn_s_setprio(1);
        acc[0][0] = __builtin_amdgcn_mfma_i32_16x16x64_i8(af0, bf0, acc[0][0], 0, 0, 0);
        acc[0][1] = __builtin_amdgcn_mfma_i32_16x16x64_i8(af0, bf1, acc[0][1], 0, 0, 0);
        acc[0][2] = __builtin_amdgcn_mfma_i32_16x16x64_i8(af0, bf2, acc[0][2], 0, 0, 0);
        acc[0][3] = __builtin_amdgcn_mfma_i32_16x16x64_i8(af0, bf3, acc[0][3], 0, 0, 0);
        acc[1][0] = __builtin_amdgcn_mfma_i32_16x16x64_i8(af1, bf0, acc[1][0], 0, 0, 0);
        acc[1][1] = __builtin_amdgcn_mfma_i32_16x16x64_i8(af1, bf1, acc[1][1], 0, 0, 0);
        acc[1][2] = __builtin_amdgcn_mfma_i32_16x16x64_i8(af1, bf2, acc[1][2], 0, 0, 0);
        acc[1][3] = __builtin_amdgcn_mfma_i32_16x16x64_i8(af1, bf3, acc[1][3], 0, 0, 0);
        acc[2][0] = __builtin_amdgcn_mfma_i32_16x16x64_i8(af2, bf0, acc[2][0], 0, 0, 0);
        acc[2][1] = __builtin_amdgcn_mfma_i32_16x16x64_i8(af2, bf1, acc[2][1], 0, 0, 0);
        acc[2][2] = __builtin_amdgcn_mfma_i32_16x16x64_i8(af2, bf2, acc[2][2], 0, 0, 0);
        acc[2][3] = __builtin_amdgcn_mfma_i32_16x16x64_i8(af2, bf3, acc[2][3], 0, 0, 0);
        acc[3][0] = __builtin_amdgcn_mfma_i32_16x16x64_i8(af3, bf0, acc[3][0], 0, 0, 0);
        acc[3][1] = __builtin_amdgcn_mfma_i32_16x16x64_i8(af3, bf1, acc[3][1], 0, 0, 0);
        acc[3][2] = __builtin_amdgcn_mfma_i32_16x16x64_i8(af3, bf2, acc[3][2], 0, 0, 0);
        acc[3][3] = __builtin_amdgcn_mfma_i32_16x16x64_i8(af3, bf3, acc[3][3], 0, 0, 0);
        __builtin_amdgcn_s_setprio(0);
        asm volatile("" ::: "memory");
        __builtin_amdgcn_s_barrier();

        // ---- phase 1: reads + stage issue, then MFMA quadrant 1 ----
        v4i af4 = *(const v4i*)(Ac + aoff[4]);
        v4i af5 = *(const v4i*)(Ac + aoff[5]);
        v4i af6 = *(const v4i*)(Ac + aoff[6]);
        v4i af7 = *(const v4i*)(Ac + aoff[7]);
        if (do_stage) STAGE_P1(stg, s + 2);
        asm volatile("" ::: "memory");
        __builtin_amdgcn_s_barrier();
        __builtin_amdgcn_s_setprio(1);
        acc[4][0] = __builtin_amdgcn_mfma_i32_16x16x64_i8(af4, bf0, acc[4][0], 0, 0, 0);
        acc[4][1] = __builtin_amdgcn_mfma_i32_16x16x64_i8(af4, bf1, acc[4][1], 0, 0, 0);
        acc[4][2] = __builtin_amdgcn_mfma_i32_16x16x64_i8(af4, bf2, acc[4][2], 0, 0, 0);
        acc[4][3] = __builtin_amdgcn_mfma_i32_16x16x64_i8(af4, bf3, acc[4][3], 0, 0, 0);
        acc[5][0] = __builtin_amdgcn_mfma_i32_16x16x64_i8(af5, bf0, acc[5][0], 0, 0, 0);
        acc[5][1] = __builtin_amdgcn_mfma_i32_16x16x64_i8(af5, bf1, acc[5][1], 0, 0, 0);
        acc[5][2] = __builtin_amdgcn_mfma_i32_16x16x64_i8(af5, bf2, acc[5][2], 0, 0, 0);
        acc[5][3] = __builtin_amdgcn_mfma_i32_16x16x64_i8(af5, bf3, acc[5][3], 0, 0, 0);
        acc[6][0] = __builtin_amdgcn_mfma_i32_16x16x64_i8(af6, bf0, acc[6][0], 0, 0, 0);
        acc[6][1] = __builtin_amdgcn_mfma_i32_16x16x64_i8(af6, bf1, acc[6][1], 0, 0, 0);
        acc[6][2] = __builtin_amdgcn_mfma_i32_16x16x64_i8(af6, bf2, acc[6][2], 0, 0, 0);
        acc[6][3] = __builtin_amdgcn_mfma_i32_16x16x64_i8(af6, bf3, acc[6][3], 0, 0, 0);
        acc[7][0] = __builtin_amdgcn_mfma_i32_16x16x64_i8(af7, bf0, acc[7][0], 0, 0, 0);
        acc[7][1] = __builtin_amdgcn_mfma_i32_16x16x64_i8(af7, bf1, acc[7][1], 0, 0, 0);
        acc[7][2] = __builtin_amdgcn_mfma_i32_16x16x64_i8(af7, bf2, acc[7][2], 0, 0, 0);
        acc[7][3] = __builtin_amdgcn_mfma_i32_16x16x64_i8(af7, bf3, acc[7][3], 0, 0, 0);
        __builtin_amdgcn_s_setprio(0);

        // step boundary: establish buf(s+1) landed without draining the queue
        if (s + 2 < NSTEP)      { asm volatile("s_waitcnt vmcnt(6)" ::: "memory"); }
        else if (s + 1 < NSTEP) { asm volatile("s_waitcnt vmcnt(0)" ::: "memory"); }
        asm volatile("" ::: "memory");
        __builtin_amdgcn_s_barrier();
        cur = (cur >= 2) ? 0 : cur + 1;
    }

    // epilogue: C col = l&15 (co), row = (l>>4)*4 + reg (pixel)   [m89 layout]
#pragma unroll
    for (int cg = 0; cg < 4; ++cg) {
        const int co = v * 64 + cg * 16 + (l & 15);
        const float sc = scale[co], sh = shift[co];
#pragma unroll
        for (int pg = 0; pg < 8; ++pg) {
            const int prow0 = p0 + pg * 16 + (l >> 4) * 4;
#pragma unroll
            for (int rr = 0; rr < 4; ++rr) {
                const float y = (float)acc[pg][cg][rr];
                out[(size_t)(prow0 + rr) * COUT + co] = fmaxf(fmaf(y, sc, sh), 0.f);
            }
        }
    }
}

extern "C" void kernel_launch(void* const* d_in, const int* in_sizes, int n_in,
                              void* d_out, int out_size, void* d_ws, size_t ws_size,
                              hipStream_t stream)
{
    const float* x      = (const float*)d_in[0];
    const float* bias1  = (const float*)d_in[1];
    const float* kernel = (const float*)d_in[2];
    const float* bn_beta = (const float*)d_in[3];
    const float* bn_mean = (const float*)d_in[4];
    const float* bn_var  = (const float*)d_in[5];
    const float* bias2   = (const float*)d_in[6];
    float* out = (float*)d_out;

    signed char* pa  = (signed char*)d_ws;                // padded i8 image
    signed char* wtp = (signed char*)d_ws + WT_OFF;       // W_t[co][k]
    float* scale = (float*)((char*)d_ws + SC_OFF);
    float* shift = (float*)((char*)d_ws + SH_OFF);

    pack_a_kernel<<<dim3(NB * HP2 / 4), dim3(256), 0, stream>>>(x, bias1, pa);
    packw_kernel<<<dim3(KTOT / 64), dim3(256), 0, stream>>>(kernel, wtp);
    bnprep_kernel<<<dim3(1), dim3(256), 0, stream>>>(bn_beta, bn_mean, bn_var, bias2,
                                                     scale, shift);
    conv_mfma_kernel<<<dim3(NPIX / BM), dim3(256), 0, stream>>>(pa, wtp, scale, shift, out);
}